// Round 4
// baseline (89.281 us; speedup 1.0000x reference)
//
#include <hip/hip_runtime.h>
#include <hip/hip_fp16.h>

// GeometryAwareCostVolume — MI355X (gfx950), R4
//
// R1-R3 post-mortem: three different tap/LDS structures (conflicted b128,
// split-quad b128, conflict-free half2 b32) all land at ~85 us => LDS side
// never mattered. Residual kernel time (~20 us over the ~60 us of in-graph
// harness poison traffic) can only live in the invariants: the scalar-dword
// channel-strided store stream (256 B/wave-inst) and launch structure.
//
// R4: thread = (h in 2, lvl in 4, w4 in 40) owns 4 consecutive pixels.
//  * stores: 18x global_store_dwordx4/thread (16 B/lane sweet spot, 1 KB/wave
//    contiguous segments) — 4x fewer store insts than R1-R3.
//  * fmap1/coords read as float4 (coalesced 640 B runs).
//  * one block per (b,g,h-pair): f2 rows staged once (fmap2 fetch halves).
// Algebra unchanged: geo==feat (write twice); integer dx -> shared lerp
// fraction, 10 pooled bins/level; pool-before-dot via fp16 half2 planes.

namespace {
constexpr int B_ = 2, C_ = 64, H_ = 80, W_ = 160;
constexpr int G_ = 8, GC_ = 8, L_ = 4, K_ = 9, R_ = 4;
constexpr int HW_ = H_ * W_;
constexpr int NCH_ = 2 * L_ * G_ * K_;     // 576
constexpr int TPB = 320;                   // thread = (hh*4 + lvl)*40 + w4
constexpr int NBINS = 160 + 80 + 40 + 20;  // 300 bins, all levels
constexpr float INV_SQRT_GC = 0.35355339059327373f;
}

__global__ __launch_bounds__(TPB) void gacv_kernel(
    const float* __restrict__ fmap1, const float* __restrict__ fmap2,
    const float* __restrict__ coords, float* __restrict__ out) {
  // pln[row][pair][bin]: channels {2p,2p+1} packed half2. 9.6 KB.
  __shared__ __half2 pln[2][4][NBINS];

  const int tid = threadIdx.x;
  const int bid = blockIdx.x;  // (b*G + g)*(H/2) + hb
  const int hb = bid % (H_ / 2);
  const int bg = bid / (H_ / 2);
  const int g = bg % G_;
  const int b = bg / G_;
  const int h0 = 2 * hb;

  // ---- stage two f2 rows: v-fastest => coalesced global + conflict-free LDS
  const float* f2base = fmap2 + (size_t)(b * C_ + g * GC_) * HW_ + h0 * W_;
  for (int idx = tid; idx < 2 * 4 * W_; idx += TPB) {
    int v = idx % W_;
    int r = idx / W_;  // 0..7
    int pair = r & 3;
    int hh = r >> 2;
    float lo = f2base[(2 * pair) * HW_ + hh * W_ + v];
    float hi = f2base[(2 * pair + 1) * HW_ + hh * W_ + v];
    pln[hh][pair][v] = __floats2half2_rn(lo, hi);
  }
  __syncthreads();
  // ---- hierarchical pair-mean pyramid (matches reference association)
  const __half2 halfc = __float2half2_rn(0.5f);
  for (int idx = tid; idx < 2 * 4 * 80; idx += TPB) {
    int t = idx % 80; int r = idx / 80; int pair = r & 3; int hh = r >> 2;
    pln[hh][pair][160 + t] =
        __hmul2(__hadd2(pln[hh][pair][2 * t], pln[hh][pair][2 * t + 1]), halfc);
  }
  __syncthreads();
  for (int idx = tid; idx < 2 * 4 * 40; idx += TPB) {
    int t = idx % 40; int r = idx / 40; int pair = r & 3; int hh = r >> 2;
    pln[hh][pair][240 + t] =
        __hmul2(__hadd2(pln[hh][pair][160 + 2 * t], pln[hh][pair][160 + 2 * t + 1]), halfc);
  }
  __syncthreads();
  for (int idx = tid; idx < 2 * 4 * 20; idx += TPB) {
    int t = idx % 20; int r = idx / 20; int pair = r & 3; int hh = r >> 2;
    pln[hh][pair][280 + t] =
        __hmul2(__hadd2(pln[hh][pair][240 + 2 * t], pln[hh][pair][240 + 2 * t + 1]), halfc);
  }
  __syncthreads();

  // ---- compute: thread owns 4 consecutive pixels at one (h,lvl)
  const int w4 = tid % 40;
  const int rl = tid / 40;  // 0..7
  const int lvl = rl & 3;
  const int hh = rl >> 2;
  const int h = h0 + hh;

  const float lscale = __int_as_float(0x3f800000 - (lvl << 23));  // 2^-lvl
  const int Wl = W_ >> lvl;
  const int ofs = 320 - (320 >> lvl);  // {0,160,240,280}

  // f1 fragments for the 4 pixels: one float4 per channel (coalesced)
  float4 f1m[GC_];
  const float* f1base = fmap1 + (size_t)(b * C_ + g * GC_) * HW_ + h * W_ + 4 * w4;
#pragma unroll
  for (int c = 0; c < GC_; ++c) {
    float4 v = *(const float4*)(f1base + c * HW_);
    f1m[c] = make_float4(v.x * INV_SQRT_GC, v.y * INV_SQRT_GC,
                         v.z * INV_SQRT_GC, v.w * INV_SQRT_GC);
  }
  const float4 cx4 = *(const float4*)(coords + (b * H_ + h) * W_ + 4 * w4);

  float4 vals[K_];  // per-k outputs for the 4 pixels
#pragma unroll
  for (int p = 0; p < 4; ++p) {
    const float cx = (p == 0) ? cx4.x : (p == 1) ? cx4.y : (p == 2) ? cx4.z : cx4.w;
    const float xl = cx * lscale;
    const float F = floorf(xl);
    const int fi = (int)F;
    const float w1 = xl - F;  // shared lerp fraction (dx taps are integers)
    const float w0 = 1.0f - w1;

    float T[2 * R_ + 2];
#pragma unroll
    for (int j = 0; j < 2 * R_ + 2; ++j) {
      int t = fi - R_ + j;
      int tc = min(max(t, 0), Wl - 1);
      int bi = ofs + tc;
      float2 c0 = __half22float2(pln[hh][0][bi]);
      float2 c1 = __half22float2(pln[hh][1][bi]);
      float2 c2 = __half22float2(pln[hh][2][bi]);
      float2 c3 = __half22float2(pln[hh][3][bi]);
      float s;
      if (p == 0)
        s = f1m[0].x * c0.x + f1m[1].x * c0.y + f1m[2].x * c1.x + f1m[3].x * c1.y +
            f1m[4].x * c2.x + f1m[5].x * c2.y + f1m[6].x * c3.x + f1m[7].x * c3.y;
      else if (p == 1)
        s = f1m[0].y * c0.x + f1m[1].y * c0.y + f1m[2].y * c1.x + f1m[3].y * c1.y +
            f1m[4].y * c2.x + f1m[5].y * c2.y + f1m[6].y * c3.x + f1m[7].y * c3.y;
      else if (p == 2)
        s = f1m[0].z * c0.x + f1m[1].z * c0.y + f1m[2].z * c1.x + f1m[3].z * c1.y +
            f1m[4].z * c2.x + f1m[5].z * c2.y + f1m[6].z * c3.x + f1m[7].z * c3.y;
      else
        s = f1m[0].w * c0.x + f1m[1].w * c0.y + f1m[2].w * c1.x + f1m[3].w * c1.y +
            f1m[4].w * c2.x + f1m[5].w * c2.y + f1m[6].w * c3.x + f1m[7].w * c3.y;
      T[j] = (t == tc) ? s : 0.0f;  // mask out-of-range taps
    }
#pragma unroll
    for (int k = 0; k < K_; ++k) {
      float v = w0 * T[k] + w1 * T[k + 1];
      if (p == 0) vals[k].x = v;
      else if (p == 1) vals[k].y = v;
      else if (p == 2) vals[k].z = v;
      else vals[k].w = v;
    }
  }

  // ---- float4 stores: 16 B/lane, 1 KB/wave contiguous segments
  float4* outb4 = (float4*)out + (size_t)b * NCH_ * (HW_ / 4) + (h * W_) / 4 + w4;
  const int chBase = lvl * (2 * G_ * K_) + g * K_;
#pragma unroll
  for (int k = 0; k < K_; ++k) {
    outb4[(size_t)(chBase + k) * (HW_ / 4)] = vals[k];             // feat copy
    outb4[(size_t)(chBase + G_ * K_ + k) * (HW_ / 4)] = vals[k];   // geo copy
  }
}

extern "C" void kernel_launch(void* const* d_in, const int* in_sizes, int n_in,
                              void* d_out, int out_size, void* d_ws, size_t ws_size,
                              hipStream_t stream) {
  const float* fmap1 = (const float*)d_in[0];
  const float* fmap2 = (const float*)d_in[1];
  const float* coords = (const float*)d_in[2];
  float* out = (float*)d_out;
  gacv_kernel<<<dim3(B_ * G_ * (H_ / 2)), dim3(TPB), 0, stream>>>(fmap1, fmap2, coords, out);
}

// Round 5
// 85.612 us; speedup vs baseline: 1.0429x; 1.0429x over previous
//
#include <hip/hip_runtime.h>
#include <hip/hip_fp16.h>

// GeometryAwareCostVolume — MI355X (gfx950), R5 (revert to best = R3 structure)
//
// Elimination matrix across R1-R4: parallelism x4 (R2), LDS-conflict-free
// half2 gathers (R3), and 1KB dwordx4 stores (R4) were ALL neutral at
// 85-89 us total. Surviving model: dur_us = fixed in-graph harness traffic
// (268 MB ws poison @ ~44 us at the 6.1 TB/s achievable write ceiling
// + 59 MB out poison + input restore + dispatch gaps ~= 62-73 us) + kernel
// at its own memory floor (59 MB stores + 13 MB reads @ 6.1 TB/s ~= 12 us).
// R4's -4 us came from 4x-redundant fmap1 reads; this revert restores the
// best-measured kernel (R3, 85.3 us ~= R1's 85.0 within noise).
//
// Algebra: geo==feat (compute once, store twice); integer dx taps -> shared
// lerp fraction, only 10 pooled bins/level; cost volume is linear in fmap2 so
// pool fmap2 rows FIRST (hierarchical pair means == reference association) —
// the 131 MB cost volume is never materialized. Pooled bins as 4 half2
// planes in LDS: taps are random-dword ds_read_b32 (~2 lanes/bank = free),
// staging is coalesced in global AND conflict-free in LDS.

namespace {
constexpr int B_ = 2, C_ = 64, H_ = 80, W_ = 160;
constexpr int G_ = 8, GC_ = 8, L_ = 4, K_ = 9, R_ = 4;
constexpr int HW_ = H_ * W_;
constexpr int NCH_ = 2 * L_ * G_ * K_;     // 576
constexpr int TPB = 320;                   // thread = (w_local in 80, level in 4)
constexpr int NBINS = 160 + 80 + 40 + 20;  // 300 bins across levels
constexpr float INV_SQRT_GC = 0.35355339059327373f;
}

__global__ __launch_bounds__(TPB) void gacv_kernel(
    const float* __restrict__ fmap1, const float* __restrict__ fmap2,
    const float* __restrict__ coords, float* __restrict__ out) {
  // plane p holds channels {2p, 2p+1} packed as half2, indexed by bin. 4.8 KB.
  __shared__ __half2 pln[4][NBINS];

  const int tid = threadIdx.x;
  const int bid = blockIdx.x;
  const int half = bid & 1;
  const int rid = bid >> 1;  // (b*G + g)*H + h
  const int h = rid % H_;
  const int bg = rid / H_;
  const int g = bg % G_;
  const int b = bg / G_;

  // ---- stage level-0 row: v-fastest => coalesced global reads AND
  // consecutive-dword LDS writes (conflict-free).
  const float* f2base = fmap2 + (size_t)(b * C_ + g * GC_) * HW_ + h * W_;
  for (int idx = tid; idx < 4 * W_; idx += TPB) {
    int v = idx % W_;
    int pair = idx / W_;
    float lo = f2base[(2 * pair) * HW_ + v];
    float hi = f2base[(2 * pair + 1) * HW_ + v];
    pln[pair][v] = __floats2half2_rn(lo, hi);
  }
  __syncthreads();
  // ---- hierarchical pair-mean pyramid (matches reference association).
  const __half2 halfc = __float2half2_rn(0.5f);
  {  // level 1: 80 bins x 4 pairs = 320 items (== TPB)
    int t = tid % 80, pair = tid / 80;
    pln[pair][160 + t] = __hmul2(__hadd2(pln[pair][2 * t], pln[pair][2 * t + 1]), halfc);
  }
  __syncthreads();
  if (tid < 160) {  // level 2: 40 x 4
    int t = tid % 40, pair = tid / 40;
    pln[pair][240 + t] = __hmul2(__hadd2(pln[pair][160 + 2 * t], pln[pair][160 + 2 * t + 1]), halfc);
  }
  __syncthreads();
  if (tid < 80) {  // level 3: 20 x 4
    int t = tid % 20, pair = tid / 20;
    pln[pair][280 + t] = __hmul2(__hadd2(pln[pair][240 + 2 * t], pln[pair][240 + 2 * t + 1]), halfc);
  }
  __syncthreads();

  // ---- compute: thread = (w_local, level)
  const int w_local = tid % 80;
  const int lvl = tid / 80;
  const int w = half * 80 + w_local;

  float f1v[GC_];
  const float* f1base = fmap1 + (size_t)(b * C_ + g * GC_) * HW_ + h * W_ + w;
#pragma unroll
  for (int c = 0; c < GC_; ++c) f1v[c] = f1base[c * HW_] * INV_SQRT_GC;

  const float cx = coords[(b * H_ + h) * W_ + w];
  const float xl = ldexpf(cx, -lvl);        // cx / 2^lvl, exact
  const int Wl = W_ >> lvl;
  const int ofs = 320 - (320 >> lvl);       // {0,160,240,280}
  const float F = floorf(xl);
  const int fi = (int)F;
  const float w1 = xl - F;  // shared lerp fraction (dx taps are integers)
  const float w0 = 1.0f - w1;

  float T[2 * R_ + 2];  // pooled-bin dots fi-4 .. fi+5, zero outside [0,Wl)
#pragma unroll
  for (int j = 0; j < 2 * R_ + 2; ++j) {
    int t = fi - R_ + j;
    int tc = min(max(t, 0), Wl - 1);
    int bi = ofs + tc;
    float2 c0 = __half22float2(pln[0][bi]);
    float2 c1 = __half22float2(pln[1][bi]);
    float2 c2 = __half22float2(pln[2][bi]);
    float2 c3 = __half22float2(pln[3][bi]);
    float s = f1v[0] * c0.x + f1v[1] * c0.y + f1v[2] * c1.x + f1v[3] * c1.y +
              f1v[4] * c2.x + f1v[5] * c2.y + f1v[6] * c3.x + f1v[7] * c3.y;
    T[j] = (t == tc) ? s : 0.0f;  // mask out-of-range taps (reference semantics)
  }

  float* outb = out + (size_t)b * NCH_ * HW_ + h * W_ + w;
  const int chBase = lvl * (2 * G_ * K_) + g * K_;
#pragma unroll
  for (int k = 0; k < K_; ++k) {
    float val = w0 * T[k] + w1 * T[k + 1];
    outb[(size_t)(chBase + k) * HW_] = val;            // feat copy
    outb[(size_t)(chBase + G_ * K_ + k) * HW_] = val;  // geo copy (identical)
  }
}

extern "C" void kernel_launch(void* const* d_in, const int* in_sizes, int n_in,
                              void* d_out, int out_size, void* d_ws, size_t ws_size,
                              hipStream_t stream) {
  const float* fmap1 = (const float*)d_in[0];
  const float* fmap2 = (const float*)d_in[1];
  const float* coords = (const float*)d_in[2];
  float* out = (float*)d_out;
  gacv_kernel<<<dim3(B_ * G_ * H_ * 2), dim3(TPB), 0, stream>>>(fmap1, fmap2, coords, out);
}